// Round 2
// baseline (3748.620 us; speedup 1.0000x reference)
//
#include <hip/hip_runtime.h>
#include <hip/hip_bf16.h>

#define VOCAB 32000
#define EMBED 512
#define HIDDEN 1024
#define NB 8
#define NT 256
#define NBLK_REC 128
#define XH_ROWS 16

typedef __attribute__((ext_vector_type(8))) short bf16x8;
typedef __attribute__((ext_vector_type(4))) float f32x4;

// ---------------- W_hy [HIDDEN][VOCAB] f32 -> Wt [VOCAB][HIDDEN] bf16 ----------------
__global__ __launch_bounds__(256) void k_transpose(const float* __restrict__ W,
                                                   __hip_bfloat16* __restrict__ Wt) {
    __shared__ float tile[32][33];
    const int n0 = blockIdx.x * 32;
    const int k0 = blockIdx.y * 32;
    const int c = threadIdx.x & 31;
    const int r0 = threadIdx.x >> 5;
#pragma unroll
    for (int rr = 0; rr < 4; ++rr) {
        const int r = r0 + rr * 8;
        tile[c][r] = W[(size_t)(k0 + r) * VOCAB + n0 + c];
    }
    __syncthreads();
#pragma unroll
    for (int rr = 0; rr < 4; ++rr) {
        const int n = r0 + rr * 8;
        Wt[(size_t)(n0 + n) * HIDDEN + k0 + c] = __float2bfloat16(tile[n][c]);
    }
}

// ---------------- xh = emb[x] @ W_xh + b_h  (fp32) ----------------
__global__ __launch_bounds__(256) void k_xh(const int* __restrict__ ids,
                                            const float* __restrict__ emb,
                                            const float* __restrict__ Wxh,
                                            const float* __restrict__ bh,
                                            float* __restrict__ xh) {
    __shared__ alignas(16) float embS[XH_ROWS][EMBED];
    __shared__ int idsS[XH_ROWS];
    const int tid = threadIdx.x;
    const int blk = blockIdx.x;
    if (tid < XH_ROWS) idsS[tid] = ids[blk * XH_ROWS + tid];
    __syncthreads();
    const float4* emb4 = (const float4*)emb;
#pragma unroll
    for (int rep = 0; rep < (XH_ROWS * EMBED / 4) / 256; ++rep) {
        const int lin = rep * 256 + tid;
        const int r = lin >> 7;
        const int e4 = lin & 127;
        *(float4*)&embS[r][e4 * 4] = emb4[(size_t)idsS[r] * (EMBED / 4) + e4];
    }
    __syncthreads();
    float4 acc[XH_ROWS] = {};
    const float4* W4 = (const float4*)Wxh;
    for (int e = 0; e < EMBED; ++e) {
        const float4 w = W4[(size_t)e * (HIDDEN / 4) + tid];
#pragma unroll
        for (int r = 0; r < XH_ROWS; ++r) {
            const float ev = embS[r][e];
            acc[r].x += ev * w.x; acc[r].y += ev * w.y;
            acc[r].z += ev * w.z; acc[r].w += ev * w.w;
        }
    }
    const float4 bv = ((const float4*)bh)[tid];
#pragma unroll
    for (int r = 0; r < XH_ROWS; ++r) {
        float4 o;
        o.x = acc[r].x + bv.x; o.y = acc[r].y + bv.y;
        o.z = acc[r].z + bv.z; o.w = acc[r].w + bv.w;
        ((float4*)xh)[(size_t)(blk * XH_ROWS + r) * (HIDDEN / 4) + tid] = o;
    }
}

// ---------------- flag-array grid barrier (release/acquire, AGENT scope) ----------------
// arrive: NBLK_REC slots, 64 B apart. go: single word at arrive + 2048 u32.
__device__ __forceinline__ void grid_barrier(unsigned* __restrict__ arrive,
                                             unsigned* __restrict__ go,
                                             unsigned token) {
    __syncthreads();
    const int tid = threadIdx.x;
    if (blockIdx.x == 0) {
        if (tid > 0 && tid < NBLK_REC) {
            while (__hip_atomic_load(&arrive[tid * 16], __ATOMIC_ACQUIRE,
                                     __HIP_MEMORY_SCOPE_AGENT) < token) {}
        }
        __syncthreads();
        if (tid == 0) {
            __hip_atomic_store(go, token, __ATOMIC_RELEASE, __HIP_MEMORY_SCOPE_AGENT);
        }
    } else {
        if (tid == 0) {
            __hip_atomic_store(&arrive[blockIdx.x * 16], token, __ATOMIC_RELEASE,
                               __HIP_MEMORY_SCOPE_AGENT);
            while (__hip_atomic_load(go, __ATOMIC_ACQUIRE,
                                     __HIP_MEMORY_SCOPE_AGENT) < token) {}
        }
    }
    __syncthreads();
}

// ---------------- persistent recurrence ----------------
__global__ __launch_bounds__(256, 1) void k_rec(const float* __restrict__ Whh,
                                                const float* __restrict__ xh,
                                                float* __restrict__ hbuf,
                                                __hip_bfloat16* __restrict__ hs,
                                                unsigned* __restrict__ bar) {
    __shared__ alignas(16) float Wst[8][1028];   // W_hh columns j0..j0+7, transposed, padded
    __shared__ alignas(16) float hS[8][1028];    // staged h (all batches)
    __shared__ float red[256];
    unsigned* arrive = bar;
    unsigned* go = bar + 2048;
    const int tid = threadIdx.x;
    const int bid = blockIdx.x;
    const int j0 = bid * 8;
    for (int lin = tid; lin < 8 * HIDDEN; lin += 256) {
        const int i = lin >> 3;
        const int jj = lin & 7;
        Wst[jj][i] = Whh[(size_t)i * HIDDEN + j0 + jj];
    }
    if (tid < 64) {
        const int b = tid >> 3, jj = tid & 7;
        hbuf[b * HIDDEN + j0 + jj] = 0.f;
    }
    grid_barrier(arrive, go, 1u);

    const int o = tid & 63;
    const int b = o >> 3;
    const int jj = o & 7;
    const int part = tid >> 6;
    const float4* Wsj = (const float4*)&Wst[jj][0];
    const float4* hSb = (const float4*)&hS[b][0];

    for (int t = 0; t < NT; ++t) {
        const float* hprev = hbuf + (t & 1) * (NB * HIDDEN);
        float* hnext = hbuf + ((t + 1) & 1) * (NB * HIDDEN);
        const float4* hp4 = (const float4*)hprev;
#pragma unroll
        for (int rep = 0; rep < 8; ++rep) {
            const int lin = rep * 256 + tid;
            const int hb = lin >> 8;
            const int i4 = lin & 255;
            *(float4*)&hS[hb][i4 * 4] = hp4[lin];
        }
        __syncthreads();
        float a0 = 0.f, a1 = 0.f, a2 = 0.f, a3 = 0.f;
#pragma unroll 8
        for (int ii = 0; ii < 64; ++ii) {
            const float4 hv = hSb[part * 64 + ii];
            const float4 wv = Wsj[part * 64 + ii];
            a0 += hv.x * wv.x; a1 += hv.y * wv.y;
            a2 += hv.z * wv.z; a3 += hv.w * wv.w;
        }
        red[tid] = (a0 + a1) + (a2 + a3);
        __syncthreads();
        if (tid < 64) {
            const float sum = red[tid] + red[tid + 64] + red[tid + 128] + red[tid + 192];
            const float val = tanhf(xh[(size_t)(b * NT + t) * HIDDEN + j0 + jj] + sum);
            hnext[b * HIDDEN + j0 + jj] = val;
            hs[(size_t)(b * NT + t) * HIDDEN + j0 + jj] = __float2bfloat16(val);
        }
        grid_barrier(arrive, go, (unsigned)(t + 2));
    }
}

// ---------------- y = hs @ Wt^T + b_y  (bf16 MFMA, 128x128 tile) ----------------
#define LDP 40   // padded LDS row: 80 B stride keeps 16 B align, breaks 8-way conflict
__global__ __launch_bounds__(256) void k_proj(const __hip_bfloat16* __restrict__ A,   // [2048][1024]
                                              const __hip_bfloat16* __restrict__ Bt,  // [32000][1024]
                                              const float* __restrict__ by,
                                              float* __restrict__ C) {
    __shared__ alignas(16) __hip_bfloat16 At[128][LDP];
    __shared__ alignas(16) __hip_bfloat16 Bts[128][LDP];
    const int tid = threadIdx.x;
    const int n0 = blockIdx.x * 128;
    const int m0 = blockIdx.y * 128;
    const int lane = tid & 63;
    const int wid = tid >> 6;
    const int wr = wid >> 1, wc = wid & 1;
    const int fr = lane & 15, fq = lane >> 4;
    f32x4 acc[4][4] = {};
    const int sr = tid >> 1;         // staging row 0..127
    const int sh = (tid & 1) * 16;   // staging k-offset: 0 or 16 (each thread covers 16 bf16)
    for (int k0 = 0; k0 < HIDDEN; k0 += 32) {
        const uint4* As = (const uint4*)(A + (size_t)(m0 + sr) * HIDDEN + k0 + sh);
        const uint4* Bs = (const uint4*)(Bt + (size_t)(n0 + sr) * HIDDEN + k0 + sh);
        uint4 a0v = As[0], a1v = As[1];
        uint4 b0v = Bs[0], b1v = Bs[1];
        *(uint4*)&At[sr][sh]      = a0v;
        *(uint4*)&At[sr][sh + 8]  = a1v;
        *(uint4*)&Bts[sr][sh]     = b0v;
        *(uint4*)&Bts[sr][sh + 8] = b1v;
        __syncthreads();
        bf16x8 af[4], bfr[4];
#pragma unroll
        for (int m = 0; m < 4; ++m) af[m] = *(const bf16x8*)&At[wr * 64 + m * 16 + fr][fq * 8];
#pragma unroll
        for (int n = 0; n < 4; ++n) bfr[n] = *(const bf16x8*)&Bts[wc * 64 + n * 16 + fr][fq * 8];
#pragma unroll
        for (int m = 0; m < 4; ++m)
#pragma unroll
            for (int n = 0; n < 4; ++n)
                acc[m][n] = __builtin_amdgcn_mfma_f32_16x16x32_bf16(af[m], bfr[n], acc[m][n], 0, 0, 0);
        __syncthreads();
    }
#pragma unroll
    for (int n = 0; n < 4; ++n) {
        const int col = n0 + wc * 64 + n * 16 + fr;
        const float bias = by[col];
#pragma unroll
        for (int m = 0; m < 4; ++m) {
            const int row = m0 + wr * 64 + m * 16 + fq * 4;
            float* cp = C + (size_t)row * VOCAB + col;
            cp[0]                 = acc[m][n][0] + bias;
            cp[(size_t)VOCAB]     = acc[m][n][1] + bias;
            cp[(size_t)2 * VOCAB] = acc[m][n][2] + bias;
            cp[(size_t)3 * VOCAB] = acc[m][n][3] + bias;
        }
    }
}

extern "C" void kernel_launch(void* const* d_in, const int* in_sizes, int n_in,
                              void* d_out, int out_size, void* d_ws, size_t ws_size,
                              hipStream_t stream) {
    const int*   x   = (const int*)d_in[0];
    const float* emb = (const float*)d_in[1];
    const float* Wxh = (const float*)d_in[2];
    const float* Whh = (const float*)d_in[3];
    const float* bh  = (const float*)d_in[4];
    const float* Why = (const float*)d_in[5];
    const float* by  = (const float*)d_in[6];
    float* y = (float*)d_out;

    char* ws = (char*)d_ws;
    // layout: xh (8 MB) | hbuf (64 KB) | hs bf16 (4 MB) | Wt bf16 (62.5 MB) | barrier (16 KB)
    const size_t off_xh   = 0;
    const size_t off_hbuf = off_xh + (size_t)NB * NT * HIDDEN * 4;          // 8 MB
    const size_t off_hs   = off_hbuf + 2 * NB * HIDDEN * 4;                 // +64 KB
    const size_t off_wt   = off_hs + (size_t)NB * NT * HIDDEN * 2;          // +4 MB
    const size_t off_bar  = off_wt + (size_t)VOCAB * HIDDEN * 2;            // +62.5 MB
    const size_t need     = off_bar + 16384;
    if (ws_size < need) return;

    float* xh = (float*)(ws + off_xh);
    float* hbuf = (float*)(ws + off_hbuf);
    __hip_bfloat16* hs = (__hip_bfloat16*)(ws + off_hs);
    __hip_bfloat16* Wt = (__hip_bfloat16*)(ws + off_wt);
    unsigned* bar = (unsigned*)(ws + off_bar);

    hipMemsetAsync(bar, 0, 16384, stream);
    k_transpose<<<dim3(VOCAB / 32, HIDDEN / 32), 256, 0, stream>>>(Why, Wt);
    k_xh<<<dim3((NB * NT) / XH_ROWS), 256, 0, stream>>>(x, emb, Wxh, bh, xh);
    k_rec<<<dim3(NBLK_REC), 256, 0, stream>>>(Whh, xh, hbuf, hs, bar);
    k_proj<<<dim3(VOCAB / 128, (NB * NT) / 128), 256, 0, stream>>>(hs, Wt, by, y);
}

// Round 3
// 1829.167 us; speedup vs baseline: 2.0494x; 2.0494x over previous
//
#include <hip/hip_runtime.h>
#include <hip/hip_bf16.h>

#define VOCAB 32000
#define EMBED 512
#define HIDDEN 1024
#define NB 8
#define NT 256
#define XH_ROWS 16

#define NCH 8      // independent chains (= batch)
#define NMEM 16    // blocks per chain
#define RCOLS 64   // hidden columns per block

typedef __attribute__((ext_vector_type(8))) short bf16x8;
typedef __attribute__((ext_vector_type(4))) float f32x4;

__device__ __forceinline__ unsigned short bf16_bits(float f) {
    __hip_bfloat16 b = __float2bfloat16(f);
    unsigned short s;
    __builtin_memcpy(&s, &b, 2);
    return s;
}

// ---------------- W_hy [HIDDEN][VOCAB] f32 -> Wt [VOCAB][HIDDEN] bf16 ----------------
__global__ __launch_bounds__(256) void k_transpose(const float* __restrict__ W,
                                                   __hip_bfloat16* __restrict__ Wt) {
    __shared__ float tile[32][33];
    const int n0 = blockIdx.x * 32;
    const int k0 = blockIdx.y * 32;
    const int c = threadIdx.x & 31;
    const int r0 = threadIdx.x >> 5;
#pragma unroll
    for (int rr = 0; rr < 4; ++rr) {
        const int r = r0 + rr * 8;
        tile[c][r] = W[(size_t)(k0 + r) * VOCAB + n0 + c];
    }
    __syncthreads();
#pragma unroll
    for (int rr = 0; rr < 4; ++rr) {
        const int n = r0 + rr * 8;
        Wt[(size_t)(n0 + n) * HIDDEN + k0 + c] = __float2bfloat16(tile[n][c]);
    }
}

// ---------------- xh = emb[x] @ W_xh + b_h  (fp32) ----------------
__global__ __launch_bounds__(256) void k_xh(const int* __restrict__ ids,
                                            const float* __restrict__ emb,
                                            const float* __restrict__ Wxh,
                                            const float* __restrict__ bh,
                                            float* __restrict__ xh) {
    __shared__ alignas(16) float embS[XH_ROWS][EMBED];
    __shared__ int idsS[XH_ROWS];
    const int tid = threadIdx.x;
    const int blk = blockIdx.x;
    if (tid < XH_ROWS) idsS[tid] = ids[blk * XH_ROWS + tid];
    __syncthreads();
    const float4* emb4 = (const float4*)emb;
#pragma unroll
    for (int rep = 0; rep < (XH_ROWS * EMBED / 4) / 256; ++rep) {
        const int lin = rep * 256 + tid;
        const int r = lin >> 7;
        const int e4 = lin & 127;
        *(float4*)&embS[r][e4 * 4] = emb4[(size_t)idsS[r] * (EMBED / 4) + e4];
    }
    __syncthreads();
    float4 acc[XH_ROWS] = {};
    const float4* W4 = (const float4*)Wxh;
    for (int e = 0; e < EMBED; ++e) {
        const float4 w = W4[(size_t)e * (HIDDEN / 4) + tid];
#pragma unroll
        for (int r = 0; r < XH_ROWS; ++r) {
            const float ev = embS[r][e];
            acc[r].x += ev * w.x; acc[r].y += ev * w.y;
            acc[r].z += ev * w.z; acc[r].w += ev * w.w;
        }
    }
    const float4 bv = ((const float4*)bh)[tid];
#pragma unroll
    for (int r = 0; r < XH_ROWS; ++r) {
        float4 o;
        o.x = acc[r].x + bv.x; o.y = acc[r].y + bv.y;
        o.z = acc[r].z + bv.z; o.w = acc[r].w + bv.w;
        ((float4*)xh)[(size_t)(blk * XH_ROWS + r) * (HIDDEN / 4) + tid] = o;
    }
}

// ---------------- persistent recurrence: 8 independent chains x 16 blocks ----------------
// All cross-block h traffic via agent-scope atomics (coherent at L3); no L2 flush needed.
// Producer wave0: h atomic stores -> s_waitcnt vmcnt(0) -> per-member flag store.
// Consumer: acquire-poll the 16 member flags, then relaxed atomic h loads.
__global__ __launch_bounds__(256, 1) void k_rec(const float* __restrict__ Whh,
                                                const float* __restrict__ xh,
                                                float* __restrict__ hbuf,
                                                __hip_bfloat16* __restrict__ hs,
                                                unsigned* __restrict__ bar) {
    __shared__ unsigned WstU[1024 * 32];   // [i][col2] two bf16 cols packed; 128 KB
    __shared__ float hS[1024];             // 4 KB
    __shared__ float red[8 * 64];          // 2 KB
    const int tid = threadIdx.x;
    const int bid = blockIdx.x;
    const int c = bid & (NCH - 1);     // chain = batch (bid%8 ~ per-XCD round robin)
    const int m = bid >> 3;            // member 0..15
    const int j0 = m * RCOLS;
    unsigned* arr = bar + c * 256;     // this chain's 16 flags, 64 B apart

    // pack W_hh slice: WstU[i*32+c2] = bf16(W[i][j0+2c2]) | bf16(W[i][j0+2c2+1])<<16
    for (int lin = tid; lin < 1024 * 32; lin += 256) {
        const int i = lin >> 5;
        const int c2 = lin & 31;
        const float2 w = *(const float2*)&Whh[(size_t)i * HIDDEN + j0 + 2 * c2];
        WstU[lin] = (unsigned)bf16_bits(w.x) | ((unsigned)bf16_bits(w.y) << 16);
    }

    float* hb = hbuf + c * 2048;       // chain's double buffer (2 x 1024 f32)
    if (tid < RCOLS)
        __hip_atomic_store(&hb[j0 + tid], 0.f, __ATOMIC_RELAXED, __HIP_MEMORY_SCOPE_AGENT);
    if (tid < 64) asm volatile("s_waitcnt vmcnt(0)" ::: "memory");
    if (tid == 0)
        __hip_atomic_store(&arr[m * 16], 1u, __ATOMIC_RELAXED, __HIP_MEMORY_SCOPE_AGENT);
    if (tid < NMEM) {
        while (__hip_atomic_load(&arr[tid * 16], __ATOMIC_ACQUIRE, __HIP_MEMORY_SCOPE_AGENT) < 1u)
            __builtin_amdgcn_s_sleep(1);
    }
    __syncthreads();

    const int col2 = tid & 31;
    const int part = tid >> 5;
    const unsigned* Wp = &WstU[part * 128 * 32 + col2];
    const float* hp = &hS[part * 128];
    float2* red2 = (float2*)red;

    for (int t = 0; t < NT; ++t) {
        const float* hcur = hb + (t & 1) * 1024;
        float* hnxt = hb + ((t + 1) & 1) * 1024;
        // prefetch xh early (normal load, off critical path)
        float xhv = 0.f;
        if (tid < RCOLS) xhv = xh[(size_t)(c * NT + t) * HIDDEN + j0 + tid];
        // fresh h from coherence point
#pragma unroll
        for (int k = 0; k < 4; ++k) {
            const int i = k * 256 + tid;
            hS[i] = __hip_atomic_load(&hcur[i], __ATOMIC_RELAXED, __HIP_MEMORY_SCOPE_AGENT);
        }
        __syncthreads();
        float a0 = 0.f, a1 = 0.f;
#pragma unroll 8
        for (int ii = 0; ii < 128; ++ii) {
            const unsigned u = Wp[ii * 32];
            const float hv = hp[ii];
            a0 = fmaf(__uint_as_float(u << 16), hv, a0);
            a1 = fmaf(__uint_as_float(u & 0xffff0000u), hv, a1);
        }
        red2[part * 32 + col2] = make_float2(a0, a1);
        __syncthreads();
        if (tid < RCOLS) {
            float s = 0.f;
#pragma unroll
            for (int p = 0; p < 8; ++p) s += red[p * 64 + tid];
            const float v = tanhf(xhv + s);
            hs[(size_t)(c * NT + t) * HIDDEN + j0 + tid] = __float2bfloat16(v);
            __hip_atomic_store(&hnxt[j0 + tid], v, __ATOMIC_RELAXED, __HIP_MEMORY_SCOPE_AGENT);
        }
        if (tid < 64) asm volatile("s_waitcnt vmcnt(0)" ::: "memory");
        if (tid == 0)
            __hip_atomic_store(&arr[m * 16], (unsigned)(t + 2), __ATOMIC_RELAXED, __HIP_MEMORY_SCOPE_AGENT);
        if (tid < NMEM) {
            const unsigned tok = (unsigned)(t + 2);
            while (__hip_atomic_load(&arr[tid * 16], __ATOMIC_ACQUIRE, __HIP_MEMORY_SCOPE_AGENT) < tok)
                __builtin_amdgcn_s_sleep(1);
        }
        __syncthreads();
    }
}

// ---------------- y = hs @ Wt^T + b_y  (bf16 MFMA, 128x128 tile) ----------------
#define LDP 40   // padded LDS row: 80 B stride keeps 16 B align, breaks 8-way conflict
__global__ __launch_bounds__(256) void k_proj(const __hip_bfloat16* __restrict__ A,   // [2048][1024]
                                              const __hip_bfloat16* __restrict__ Bt,  // [32000][1024]
                                              const float* __restrict__ by,
                                              float* __restrict__ C) {
    __shared__ alignas(16) __hip_bfloat16 At[128][LDP];
    __shared__ alignas(16) __hip_bfloat16 Bts[128][LDP];
    const int tid = threadIdx.x;
    const int n0 = blockIdx.x * 128;
    const int m0 = blockIdx.y * 128;
    const int lane = tid & 63;
    const int wid = tid >> 6;
    const int wr = wid >> 1, wc = wid & 1;
    const int fr = lane & 15, fq = lane >> 4;
    f32x4 acc[4][4] = {};
    const int sr = tid >> 1;         // staging row 0..127
    const int sh = (tid & 1) * 16;   // staging k-offset: 0 or 16 (16 bf16 per thread)
    for (int k0 = 0; k0 < HIDDEN; k0 += 32) {
        const uint4* As = (const uint4*)(A + (size_t)(m0 + sr) * HIDDEN + k0 + sh);
        const uint4* Bs = (const uint4*)(Bt + (size_t)(n0 + sr) * HIDDEN + k0 + sh);
        uint4 a0v = As[0], a1v = As[1];
        uint4 b0v = Bs[0], b1v = Bs[1];
        *(uint4*)&At[sr][sh]      = a0v;
        *(uint4*)&At[sr][sh + 8]  = a1v;
        *(uint4*)&Bts[sr][sh]     = b0v;
        *(uint4*)&Bts[sr][sh + 8] = b1v;
        __syncthreads();
        bf16x8 af[4], bfr[4];
#pragma unroll
        for (int m = 0; m < 4; ++m) af[m] = *(const bf16x8*)&At[wr * 64 + m * 16 + fr][fq * 8];
#pragma unroll
        for (int n = 0; n < 4; ++n) bfr[n] = *(const bf16x8*)&Bts[wc * 64 + n * 16 + fr][fq * 8];
#pragma unroll
        for (int m = 0; m < 4; ++m)
#pragma unroll
            for (int n = 0; n < 4; ++n)
                acc[m][n] = __builtin_amdgcn_mfma_f32_16x16x32_bf16(af[m], bfr[n], acc[m][n], 0, 0, 0);
        __syncthreads();
    }
#pragma unroll
    for (int n = 0; n < 4; ++n) {
        const int col = n0 + wc * 64 + n * 16 + fr;
        const float bias = by[col];
#pragma unroll
        for (int m = 0; m < 4; ++m) {
            const int row = m0 + wr * 64 + m * 16 + fq * 4;
            float* cp = C + (size_t)row * VOCAB + col;
            cp[0]                 = acc[m][n][0] + bias;
            cp[(size_t)VOCAB]     = acc[m][n][1] + bias;
            cp[(size_t)2 * VOCAB] = acc[m][n][2] + bias;
            cp[(size_t)3 * VOCAB] = acc[m][n][3] + bias;
        }
    }
}

extern "C" void kernel_launch(void* const* d_in, const int* in_sizes, int n_in,
                              void* d_out, int out_size, void* d_ws, size_t ws_size,
                              hipStream_t stream) {
    const int*   x   = (const int*)d_in[0];
    const float* emb = (const float*)d_in[1];
    const float* Wxh = (const float*)d_in[2];
    const float* Whh = (const float*)d_in[3];
    const float* bh  = (const float*)d_in[4];
    const float* Why = (const float*)d_in[5];
    const float* by  = (const float*)d_in[6];
    float* y = (float*)d_out;

    char* ws = (char*)d_ws;
    // layout: xh (8 MB) | hbuf (64 KB) | hs bf16 (4 MB) | Wt bf16 (62.5 MB) | flags (16 KB)
    const size_t off_xh   = 0;
    const size_t off_hbuf = off_xh + (size_t)NB * NT * HIDDEN * 4;
    const size_t off_hs   = off_hbuf + 2 * NB * HIDDEN * 4;
    const size_t off_wt   = off_hs + (size_t)NB * NT * HIDDEN * 2;
    const size_t off_bar  = off_wt + (size_t)VOCAB * HIDDEN * 2;
    const size_t need     = off_bar + 16384;
    if (ws_size < need) return;

    float* xh = (float*)(ws + off_xh);
    float* hbuf = (float*)(ws + off_hbuf);
    __hip_bfloat16* hs = (__hip_bfloat16*)(ws + off_hs);
    __hip_bfloat16* Wt = (__hip_bfloat16*)(ws + off_wt);
    unsigned* bar = (unsigned*)(ws + off_bar);

    hipMemsetAsync(bar, 0, 16384, stream);
    k_transpose<<<dim3(VOCAB / 32, HIDDEN / 32), 256, 0, stream>>>(Why, Wt);
    k_xh<<<dim3((NB * NT) / XH_ROWS), 256, 0, stream>>>(x, emb, Wxh, bh, xh);
    k_rec<<<dim3(NCH * NMEM), 256, 0, stream>>>(Whh, xh, hbuf, hs, bar);
    k_proj<<<dim3(VOCAB / 128, (NB * NT) / 128), 256, 0, stream>>>(hs, Wt, by, y);
}

// Round 4
// 1408.143 us; speedup vs baseline: 2.6621x; 1.2990x over previous
//
#include <hip/hip_runtime.h>
#include <hip/hip_bf16.h>

#define VOCAB 32000
#define EMBED 512
#define HIDDEN 1024
#define NB 8
#define NT 256
#define XH_ROWS 16

#define NCH 8      // independent chains (= batch)
#define NMEM 16    // blocks per chain
#define RCOLS 64   // hidden columns per block

typedef __attribute__((ext_vector_type(8))) short bf16x8;
typedef __attribute__((ext_vector_type(4))) float f32x4;

__device__ __forceinline__ unsigned short bf16_bits(float f) {
    __hip_bfloat16 b = __float2bfloat16(f);
    unsigned short s;
    __builtin_memcpy(&s, &b, 2);
    return s;
}

// ---------------- xh = emb[x] @ W_xh + b_h  (fp32) ----------------
__global__ __launch_bounds__(256) void k_xh(const int* __restrict__ ids,
                                            const float* __restrict__ emb,
                                            const float* __restrict__ Wxh,
                                            const float* __restrict__ bh,
                                            float* __restrict__ xh) {
    __shared__ alignas(16) float embS[XH_ROWS][EMBED];
    __shared__ int idsS[XH_ROWS];
    const int tid = threadIdx.x;
    const int blk = blockIdx.x;
    if (tid < XH_ROWS) idsS[tid] = ids[blk * XH_ROWS + tid];
    __syncthreads();
    const float4* emb4 = (const float4*)emb;
#pragma unroll
    for (int rep = 0; rep < (XH_ROWS * EMBED / 4) / 256; ++rep) {
        const int lin = rep * 256 + tid;
        const int r = lin >> 7;
        const int e4 = lin & 127;
        *(float4*)&embS[r][e4 * 4] = emb4[(size_t)idsS[r] * (EMBED / 4) + e4];
    }
    __syncthreads();
    float4 acc[XH_ROWS] = {};
    const float4* W4 = (const float4*)Wxh;
    for (int e = 0; e < EMBED; ++e) {
        const float4 w = W4[(size_t)e * (HIDDEN / 4) + tid];
#pragma unroll
        for (int r = 0; r < XH_ROWS; ++r) {
            const float ev = embS[r][e];
            acc[r].x += ev * w.x; acc[r].y += ev * w.y;
            acc[r].z += ev * w.z; acc[r].w += ev * w.w;
        }
    }
    const float4 bv = ((const float4*)bh)[tid];
#pragma unroll
    for (int r = 0; r < XH_ROWS; ++r) {
        float4 o;
        o.x = acc[r].x + bv.x; o.y = acc[r].y + bv.y;
        o.z = acc[r].z + bv.z; o.w = acc[r].w + bv.w;
        ((float4*)xh)[(size_t)(blk * XH_ROWS + r) * (HIDDEN / 4) + tid] = o;
    }
}

// ---------------- persistent recurrence: token-in-data h exchange ----------------
// Each h element is one u32: bf16(h)<<16 | step_token. Producers fire-and-forget
// relaxed agent-scope stores; consumers poll exactly the words they need until
// the token matches. Double buffer + exact-match token is deadlock-free:
// h_{t+2} overwrites h_t only after all members produced h_{t+1}, which implies
// they fully consumed h_t. Self-initializing across replays (stale tokens
// are 255/256, expected start token is 0).
__global__ __launch_bounds__(256, 1) void k_rec(const float* __restrict__ Whh,
                                                const float* __restrict__ xh,
                                                unsigned* __restrict__ hx,
                                                __hip_bfloat16* __restrict__ hs) {
    __shared__ unsigned WstU[1024 * 32];   // [row i][col-pair c2]: 2 bf16 packed; 128 KB
    __shared__ float hS[1024];
    __shared__ float red[8 * 64];
    const int tid = threadIdx.x;
    const int bid = blockIdx.x;
    const int c = bid & (NCH - 1);     // chain (bid%8 ~ XCD round robin)
    const int m = bid >> 3;            // member 0..15
    const int j0 = m * RCOLS;
    unsigned* hxc = hx + c * 2048;     // [2][1024] packed words

    // h_{-1} = 0, token 0, lives in buf[1]
    if (tid < RCOLS)
        __hip_atomic_store(&hxc[1024 + j0 + tid], 0u, __ATOMIC_RELAXED, __HIP_MEMORY_SCOPE_AGENT);

    // pack W_hh slice: WstU[i*32+c2] = bf16(W[i][j0+2c2]) | bf16(W[i][j0+2c2+1])<<16
    for (int lin = tid; lin < 1024 * 32; lin += 256) {
        const int i = lin >> 5;
        const int c2 = lin & 31;
        const float2 w = *(const float2*)&Whh[(size_t)i * HIDDEN + j0 + 2 * c2];
        WstU[lin] = (unsigned)bf16_bits(w.x) | ((unsigned)bf16_bits(w.y) << 16);
    }

    const int col2 = tid & 31;
    const int part = tid >> 5;
    const unsigned* Wp = &WstU[part * 128 * 32 + col2];
    const float* hp = &hS[part * 128];
    float2* red2 = (float2*)red;

    for (int t = 0; t < NT; ++t) {
        unsigned* rbuf = hxc + ((t + 1) & 1) * 1024;   // holds h_{t-1}, tokens == t
        unsigned* wbuf = hxc + (t & 1) * 1024;         // we write h_t, token t+1
        const unsigned tok = (unsigned)t;
        float xhv = 0.f;
        if (tid < RCOLS) xhv = xh[(size_t)(c * NT + t) * HIDDEN + j0 + tid];
        // poll + stage: 4 words per thread; data is its own flag
#pragma unroll
        for (int k = 0; k < 4; ++k) {
            const int i = k * 256 + tid;
            unsigned u = __hip_atomic_load(&rbuf[i], __ATOMIC_RELAXED, __HIP_MEMORY_SCOPE_AGENT);
            while ((u & 0xffffu) != tok) {
                __builtin_amdgcn_s_sleep(1);
                u = __hip_atomic_load(&rbuf[i], __ATOMIC_RELAXED, __HIP_MEMORY_SCOPE_AGENT);
            }
            hS[i] = __uint_as_float(u & 0xffff0000u);
        }
        __syncthreads();
        float a0 = 0.f, a1 = 0.f;
#pragma unroll 8
        for (int ii = 0; ii < 128; ++ii) {
            const unsigned u = Wp[ii * 32];
            const float hv = hp[ii];
            a0 = fmaf(__uint_as_float(u << 16), hv, a0);
            a1 = fmaf(__uint_as_float(u & 0xffff0000u), hv, a1);
        }
        red2[part * 32 + col2] = make_float2(a0, a1);
        __syncthreads();
        if (tid < RCOLS) {
            float s = 0.f;
#pragma unroll
            for (int p = 0; p < 8; ++p) s += red[p * 64 + tid];
            const float v = tanhf(xhv + s);
            const unsigned hb = (unsigned)bf16_bits(v);
            ((unsigned short*)hs)[(size_t)(c * NT + t) * HIDDEN + j0 + tid] = (unsigned short)hb;
            __hip_atomic_store(&wbuf[j0 + tid], (hb << 16) | (unsigned)(t + 1),
                               __ATOMIC_RELAXED, __HIP_MEMORY_SCOPE_AGENT);
        }
        // no barrier: next iteration's hS writes are gated by the token poll,
        // which can't succeed until this block's own producers have stored.
    }
}

// ---------------- y = hs @ W_hy + b_y  (bf16 MFMA, fused B transpose+cast) ----------------
#define LDP 40   // padded LDS row: 80 B stride, breaks the 8-way read conflict
__global__ __launch_bounds__(256) void k_proj(const __hip_bfloat16* __restrict__ A,   // [2048][1024]
                                              const float* __restrict__ B,            // [1024][32000]
                                              const float* __restrict__ by,
                                              float* __restrict__ C) {
    __shared__ alignas(16) __hip_bfloat16 At[128][LDP];
    __shared__ alignas(16) __hip_bfloat16 Bts[128][LDP];
    const int tid = threadIdx.x;
    const int m0 = blockIdx.x * 128;   // m fastest: 16 consecutive blocks share a B panel
    const int n0 = blockIdx.y * 128;
    const int lane = tid & 63;
    const int wid = tid >> 6;
    const int wr = wid >> 1, wc = wid & 1;
    const int fr = lane & 15, fq = lane >> 4;
    f32x4 acc[4][4] = {};
    const int sr = tid >> 1;         // A staging row 0..127
    const int sh = (tid & 1) * 16;   // A staging k-offset (16 bf16 per thread)
    const int bkr = tid >> 3;        // B staging k-row 0..31
    const int bc0 = (tid & 7) * 4;   // B staging col base
    for (int k0 = 0; k0 < HIDDEN; k0 += 32) {
        const uint4* As = (const uint4*)(A + (size_t)(m0 + sr) * HIDDEN + k0 + sh);
        uint4 a0v = As[0], a1v = As[1];
        float4 bv[4];
#pragma unroll
        for (int p = 0; p < 4; ++p)
            bv[p] = *(const float4*)(B + (size_t)(k0 + bkr) * VOCAB + n0 + bc0 + p * 32);
        *(uint4*)&At[sr][sh]     = a0v;
        *(uint4*)&At[sr][sh + 8] = a1v;
#pragma unroll
        for (int p = 0; p < 4; ++p) {
            const int cc = bc0 + p * 32;
            Bts[cc + 0][bkr] = __float2bfloat16(bv[p].x);
            Bts[cc + 1][bkr] = __float2bfloat16(bv[p].y);
            Bts[cc + 2][bkr] = __float2bfloat16(bv[p].z);
            Bts[cc + 3][bkr] = __float2bfloat16(bv[p].w);
        }
        __syncthreads();
        bf16x8 af[4], bfr[4];
#pragma unroll
        for (int mm = 0; mm < 4; ++mm) af[mm] = *(const bf16x8*)&At[wr * 64 + mm * 16 + fr][fq * 8];
#pragma unroll
        for (int nn = 0; nn < 4; ++nn) bfr[nn] = *(const bf16x8*)&Bts[wc * 64 + nn * 16 + fr][fq * 8];
#pragma unroll
        for (int mm = 0; mm < 4; ++mm)
#pragma unroll
            for (int nn = 0; nn < 4; ++nn)
                acc[mm][nn] = __builtin_amdgcn_mfma_f32_16x16x32_bf16(af[mm], bfr[nn], acc[mm][nn], 0, 0, 0);
        __syncthreads();
    }
#pragma unroll
    for (int nn = 0; nn < 4; ++nn) {
        const int col = n0 + wc * 64 + nn * 16 + fr;
        const float bias = by[col];
#pragma unroll
        for (int mm = 0; mm < 4; ++mm) {
            const int row = m0 + wr * 64 + mm * 16 + fq * 4;
            float* cp = C + (size_t)row * VOCAB + col;
            cp[0]                 = acc[mm][nn][0] + bias;
            cp[(size_t)VOCAB]     = acc[mm][nn][1] + bias;
            cp[(size_t)2 * VOCAB] = acc[mm][nn][2] + bias;
            cp[(size_t)3 * VOCAB] = acc[mm][nn][3] + bias;
        }
    }
}

extern "C" void kernel_launch(void* const* d_in, const int* in_sizes, int n_in,
                              void* d_out, int out_size, void* d_ws, size_t ws_size,
                              hipStream_t stream) {
    const int*   x   = (const int*)d_in[0];
    const float* emb = (const float*)d_in[1];
    const float* Wxh = (const float*)d_in[2];
    const float* Whh = (const float*)d_in[3];
    const float* bh  = (const float*)d_in[4];
    const float* Why = (const float*)d_in[5];
    const float* by  = (const float*)d_in[6];
    float* y = (float*)d_out;

    char* ws = (char*)d_ws;
    // layout: xh (8 MB) | hx packed u32[8][2][1024] (64 KB) | hs bf16 (4 MB)
    const size_t off_xh = 0;
    const size_t off_hx = off_xh + (size_t)NB * NT * HIDDEN * 4;
    const size_t off_hs = off_hx + (size_t)NCH * 2 * HIDDEN * 4;
    const size_t need   = off_hs + (size_t)NB * NT * HIDDEN * 2;
    if (ws_size < need) return;

    float* xh = (float*)(ws + off_xh);
    unsigned* hx = (unsigned*)(ws + off_hx);
    __hip_bfloat16* hs = (__hip_bfloat16*)(ws + off_hs);

    k_xh<<<dim3((NB * NT) / XH_ROWS), 256, 0, stream>>>(x, emb, Wxh, bh, xh);
    k_rec<<<dim3(NCH * NMEM), 256, 0, stream>>>(Whh, xh, hx, hs);
    k_proj<<<dim3((NB * NT) / 128, VOCAB / 128), 256, 0, stream>>>(hs, Why, by, y);
}

// Round 5
// 1207.310 us; speedup vs baseline: 3.1049x; 1.1663x over previous
//
#include <hip/hip_runtime.h>
#include <hip/hip_bf16.h>

#define VOCAB 32000
#define EMBED 512
#define HIDDEN 1024
#define NB 8
#define NT 256
#define XH_ROWS 16

#define NCH 8      // independent chains (= batch)
#define NMEM 16    // blocks per chain
#define RCOLS 64   // hidden columns per block

typedef __attribute__((ext_vector_type(8))) short bf16x8;
typedef __attribute__((ext_vector_type(4))) float f32x4;

__device__ __forceinline__ unsigned short bf16_bits(float f) {
    __hip_bfloat16 b = __float2bfloat16(f);
    unsigned short s;
    __builtin_memcpy(&s, &b, 2);
    return s;
}

// ---------------- xh = emb[x] @ W_xh + b_h  (fp32) ----------------
__global__ __launch_bounds__(256) void k_xh(const int* __restrict__ ids,
                                            const float* __restrict__ emb,
                                            const float* __restrict__ Wxh,
                                            const float* __restrict__ bh,
                                            float* __restrict__ xh) {
    __shared__ alignas(16) float embS[XH_ROWS][EMBED];
    __shared__ int idsS[XH_ROWS];
    const int tid = threadIdx.x;
    const int blk = blockIdx.x;
    if (tid < XH_ROWS) idsS[tid] = ids[blk * XH_ROWS + tid];
    __syncthreads();
    const float4* emb4 = (const float4*)emb;
#pragma unroll
    for (int rep = 0; rep < (XH_ROWS * EMBED / 4) / 256; ++rep) {
        const int lin = rep * 256 + tid;
        const int r = lin >> 7;
        const int e4 = lin & 127;
        *(float4*)&embS[r][e4 * 4] = emb4[(size_t)idsS[r] * (EMBED / 4) + e4];
    }
    __syncthreads();
    float4 acc[XH_ROWS] = {};
    const float4* W4 = (const float4*)Wxh;
    for (int e = 0; e < EMBED; ++e) {
        const float4 w = W4[(size_t)e * (HIDDEN / 4) + tid];
#pragma unroll
        for (int r = 0; r < XH_ROWS; ++r) {
            const float ev = embS[r][e];
            acc[r].x += ev * w.x; acc[r].y += ev * w.y;
            acc[r].z += ev * w.z; acc[r].w += ev * w.w;
        }
    }
    const float4 bv = ((const float4*)bh)[tid];
#pragma unroll
    for (int r = 0; r < XH_ROWS; ++r) {
        float4 o;
        o.x = acc[r].x + bv.x; o.y = acc[r].y + bv.y;
        o.z = acc[r].z + bv.z; o.w = acc[r].w + bv.w;
        ((float4*)xh)[(size_t)(blk * XH_ROWS + r) * (HIDDEN / 4) + tid] = o;
    }
}

// ---------------- persistent recurrence: u64 token-in-data h exchange ----------------
// One u64 word = token(low16) | bf16 h[2w]<<16 | bf16 h[2w+1]<<32. Producers
// fire-and-forget relaxed agent stores (no fence/flag/vmcnt). Consumers poll
// 2 independent u64 words per thread in ONE combined retry loop -> ~1 RTT.
// Double buffer + exact-token match is deadlock-free (induction over steps);
// self-initializing across graph replays (stale tokens 255/256 != 0/1).
__global__ __launch_bounds__(256, 1) void k_rec(const float* __restrict__ Whh,
                                                const float* __restrict__ xh,
                                                unsigned long long* __restrict__ hx,
                                                __hip_bfloat16* __restrict__ hs) {
    __shared__ unsigned WstU[1024 * 32];   // [row i][col-pair c2]: 2 bf16 packed; 128 KB
    __shared__ float hS[1024];
    __shared__ float red[8 * 64];
    const int tid = threadIdx.x;
    const int bid = blockIdx.x;
    const int c = bid & (NCH - 1);     // chain (bid%8 ~ XCD round robin)
    const int m = bid >> 3;            // member 0..15
    const int j0 = m * RCOLS;
    unsigned long long* hxc = hx + (size_t)c * 1024;   // [2][512] u64 words

    // h_{-1} = 0 with token 0 lives in buf[1]; this member's 32 words
    if (tid < 32)
        __hip_atomic_store(&hxc[512 + m * 32 + tid], 0ull, __ATOMIC_RELAXED,
                           __HIP_MEMORY_SCOPE_AGENT);

    // pack W_hh slice: WstU[i*32+c2] = bf16(W[i][j0+2c2]) | bf16(W[i][j0+2c2+1])<<16
    for (int lin = tid; lin < 1024 * 32; lin += 256) {
        const int i = lin >> 5;
        const int c2 = lin & 31;
        const float2 w = *(const float2*)&Whh[(size_t)i * HIDDEN + j0 + 2 * c2];
        WstU[lin] = (unsigned)bf16_bits(w.x) | ((unsigned)bf16_bits(w.y) << 16);
    }

    const int col2 = tid & 31;
    const int part = tid >> 5;
    const unsigned* Wp = &WstU[part * 128 * 32 + col2];
    const float* hp = &hS[part * 128];
    float2* red2 = (float2*)red;
    const int w0 = tid;          // u64 word indices this thread polls
    const int w1 = tid + 256;

    for (int t = 0; t < NT; ++t) {
        unsigned long long* rbuf = hxc + ((t + 1) & 1) * 512;  // h_{t-1}, tokens == t
        unsigned long long* wbuf = hxc + (t & 1) * 512;        // we write h_t, token t+1
        const unsigned long long tok = (unsigned long long)(unsigned)t;
        float xhv = 0.f;
        if (tid < RCOLS) xhv = xh[(size_t)(c * NT + t) * HIDDEN + j0 + tid];
        // combined poll: both loads independent & in flight before the check
        unsigned long long a = __hip_atomic_load(&rbuf[w0], __ATOMIC_RELAXED, __HIP_MEMORY_SCOPE_AGENT);
        unsigned long long b = __hip_atomic_load(&rbuf[w1], __ATOMIC_RELAXED, __HIP_MEMORY_SCOPE_AGENT);
        while (((a & 0xffffull) != tok) | ((b & 0xffffull) != tok)) {
            __builtin_amdgcn_s_sleep(1);
            if ((a & 0xffffull) != tok)
                a = __hip_atomic_load(&rbuf[w0], __ATOMIC_RELAXED, __HIP_MEMORY_SCOPE_AGENT);
            if ((b & 0xffffull) != tok)
                b = __hip_atomic_load(&rbuf[w1], __ATOMIC_RELAXED, __HIP_MEMORY_SCOPE_AGENT);
        }
        hS[2 * w0]     = __uint_as_float(((unsigned)(a >> 16) & 0xffffu) << 16);
        hS[2 * w0 + 1] = __uint_as_float(((unsigned)(a >> 32) & 0xffffu) << 16);
        hS[2 * w1]     = __uint_as_float(((unsigned)(b >> 16) & 0xffffu) << 16);
        hS[2 * w1 + 1] = __uint_as_float(((unsigned)(b >> 32) & 0xffffu) << 16);
        __syncthreads();
        float a0 = 0.f, a1 = 0.f;
#pragma unroll 8
        for (int ii = 0; ii < 128; ++ii) {
            const unsigned u = Wp[ii * 32];
            const float hv = hp[ii];
            a0 = fmaf(__uint_as_float(u << 16), hv, a0);
            a1 = fmaf(__uint_as_float(u & 0xffff0000u), hv, a1);
        }
        red2[part * 32 + col2] = make_float2(a0, a1);
        __syncthreads();
        if (tid < RCOLS) {
            float s = 0.f;
#pragma unroll
            for (int p = 0; p < 8; ++p) s += red[p * 64 + tid];
            const float v = tanhf(xhv + s);
            const unsigned hb = (unsigned)bf16_bits(v);
            ((unsigned short*)hs)[(size_t)(c * NT + t) * HIDDEN + j0 + tid] = (unsigned short)hb;
            const unsigned pb = (unsigned)__shfl_xor((int)hb, 1, 64);
            if ((tid & 1) == 0) {
                const unsigned long long wv = (unsigned long long)(unsigned)(t + 1)
                                            | ((unsigned long long)hb << 16)
                                            | ((unsigned long long)pb << 32);
                __hip_atomic_store(&wbuf[m * 32 + (tid >> 1)], wv, __ATOMIC_RELAXED,
                                   __HIP_MEMORY_SCOPE_AGENT);
            }
        }
        // no block barrier needed here: next step's hS writes are gated by the
        // token poll, which can't pass until this block produced its words.
    }
}

// ---------------- y = hs @ W_hy + b_y  (bf16 MFMA, fused B transpose+cast) ----------------
#define LDP 40   // padded LDS row: 80 B stride, breaks the 8-way read conflict
__global__ __launch_bounds__(256) void k_proj(const __hip_bfloat16* __restrict__ A,   // [2048][1024]
                                              const float* __restrict__ B,            // [1024][32000]
                                              const float* __restrict__ by,
                                              float* __restrict__ C) {
    __shared__ alignas(16) __hip_bfloat16 At[128][LDP];
    __shared__ alignas(16) __hip_bfloat16 Bts[128][LDP];
    const int tid = threadIdx.x;
    const int m0 = blockIdx.x * 128;   // m fastest: 16 consecutive blocks share a B panel
    const int n0 = blockIdx.y * 128;
    const int lane = tid & 63;
    const int wid = tid >> 6;
    const int wr = wid >> 1, wc = wid & 1;
    const int fr = lane & 15, fq = lane >> 4;
    f32x4 acc[4][4] = {};
    const int sr = tid >> 1;         // A staging row 0..127
    const int sh = (tid & 1) * 16;   // A staging k-offset (16 bf16 per thread)
    const int bkr = tid >> 3;        // B staging k-row 0..31
    const int bc0 = (tid & 7) * 4;   // B staging col base
    for (int k0 = 0; k0 < HIDDEN; k0 += 32) {
        const uint4* As = (const uint4*)(A + (size_t)(m0 + sr) * HIDDEN + k0 + sh);
        uint4 a0v = As[0], a1v = As[1];
        float4 bv[4];
#pragma unroll
        for (int p = 0; p < 4; ++p)
            bv[p] = *(const float4*)(B + (size_t)(k0 + bkr) * VOCAB + n0 + bc0 + p * 32);
        *(uint4*)&At[sr][sh]     = a0v;
        *(uint4*)&At[sr][sh + 8] = a1v;
#pragma unroll
        for (int p = 0; p < 4; ++p) {
            const int cc = bc0 + p * 32;
            Bts[cc + 0][bkr] = __float2bfloat16(bv[p].x);
            Bts[cc + 1][bkr] = __float2bfloat16(bv[p].y);
            Bts[cc + 2][bkr] = __float2bfloat16(bv[p].z);
            Bts[cc + 3][bkr] = __float2bfloat16(bv[p].w);
        }
        __syncthreads();
        bf16x8 af[4], bfr[4];
#pragma unroll
        for (int mm = 0; mm < 4; ++mm) af[mm] = *(const bf16x8*)&At[wr * 64 + mm * 16 + fr][fq * 8];
#pragma unroll
        for (int nn = 0; nn < 4; ++nn) bfr[nn] = *(const bf16x8*)&Bts[wc * 64 + nn * 16 + fr][fq * 8];
#pragma unroll
        for (int mm = 0; mm < 4; ++mm)
#pragma unroll
            for (int nn = 0; nn < 4; ++nn)
                acc[mm][nn] = __builtin_amdgcn_mfma_f32_16x16x32_bf16(af[mm], bfr[nn], acc[mm][nn], 0, 0, 0);
        __syncthreads();
    }
#pragma unroll
    for (int nn = 0; nn < 4; ++nn) {
        const int col = n0 + wc * 64 + nn * 16 + fr;
        const float bias = by[col];
#pragma unroll
        for (int mm = 0; mm < 4; ++mm) {
            const int row = m0 + wr * 64 + mm * 16 + fq * 4;
            float* cp = C + (size_t)row * VOCAB + col;
            cp[0]                 = acc[mm][nn][0] + bias;
            cp[(size_t)VOCAB]     = acc[mm][nn][1] + bias;
            cp[(size_t)2 * VOCAB] = acc[mm][nn][2] + bias;
            cp[(size_t)3 * VOCAB] = acc[mm][nn][3] + bias;
        }
    }
}

extern "C" void kernel_launch(void* const* d_in, const int* in_sizes, int n_in,
                              void* d_out, int out_size, void* d_ws, size_t ws_size,
                              hipStream_t stream) {
    const int*   x   = (const int*)d_in[0];
    const float* emb = (const float*)d_in[1];
    const float* Wxh = (const float*)d_in[2];
    const float* Whh = (const float*)d_in[3];
    const float* bh  = (const float*)d_in[4];
    const float* Why = (const float*)d_in[5];
    const float* by  = (const float*)d_in[6];
    float* y = (float*)d_out;

    char* ws = (char*)d_ws;
    // layout: xh (8 MB) | hx u64[8][2][512] (64 KB) | hs bf16 (4 MB)
    const size_t off_xh = 0;
    const size_t off_hx = off_xh + (size_t)NB * NT * HIDDEN * 4;
    const size_t off_hs = off_hx + (size_t)NCH * 2 * 512 * 8;
    const size_t need   = off_hs + (size_t)NB * NT * HIDDEN * 2;
    if (ws_size < need) return;

    float* xh = (float*)(ws + off_xh);
    unsigned long long* hx = (unsigned long long*)(ws + off_hx);
    __hip_bfloat16* hs = (__hip_bfloat16*)(ws + off_hs);

    k_xh<<<dim3((NB * NT) / XH_ROWS), 256, 0, stream>>>(x, emb, Wxh, bh, xh);
    k_rec<<<dim3(NCH * NMEM), 256, 0, stream>>>(Whh, xh, hx, hs);
    k_proj<<<dim3((NB * NT) / 128, VOCAB / 128), 256, 0, stream>>>(hs, Why, by, y);
}

// Round 6
// 1085.165 us; speedup vs baseline: 3.4544x; 1.1126x over previous
//
#include <hip/hip_runtime.h>
#include <hip/hip_bf16.h>

#define VOCAB 32000
#define EMBED 512
#define HIDDEN 1024
#define NB 8
#define NT 256
#define XH_ROWS 16

#define NCH 8      // independent chains (= batch)
#define NMEM 32    // blocks per chain
#define RCOLS 32   // hidden columns per block

typedef __attribute__((ext_vector_type(8))) short bf16x8;
typedef __attribute__((ext_vector_type(4))) float f32x4;

__device__ __forceinline__ unsigned short bf16_bits(float f) {
    __hip_bfloat16 b = __float2bfloat16(f);
    unsigned short s;
    __builtin_memcpy(&s, &b, 2);
    return s;
}

// ---------------- xh = emb[x] @ W_xh + b_h  (fp32) ----------------
__global__ __launch_bounds__(256) void k_xh(const int* __restrict__ ids,
                                            const float* __restrict__ emb,
                                            const float* __restrict__ Wxh,
                                            const float* __restrict__ bh,
                                            float* __restrict__ xh) {
    __shared__ alignas(16) float embS[XH_ROWS][EMBED];
    __shared__ int idsS[XH_ROWS];
    const int tid = threadIdx.x;
    const int blk = blockIdx.x;
    if (tid < XH_ROWS) idsS[tid] = ids[blk * XH_ROWS + tid];
    __syncthreads();
    const float4* emb4 = (const float4*)emb;
#pragma unroll
    for (int rep = 0; rep < (XH_ROWS * EMBED / 4) / 256; ++rep) {
        const int lin = rep * 256 + tid;
        const int r = lin >> 7;
        const int e4 = lin & 127;
        *(float4*)&embS[r][e4 * 4] = emb4[(size_t)idsS[r] * (EMBED / 4) + e4];
    }
    __syncthreads();
    float4 acc[XH_ROWS] = {};
    const float4* W4 = (const float4*)Wxh;
    for (int e = 0; e < EMBED; ++e) {
        const float4 w = W4[(size_t)e * (HIDDEN / 4) + tid];
#pragma unroll
        for (int r = 0; r < XH_ROWS; ++r) {
            const float ev = embS[r][e];
            acc[r].x += ev * w.x; acc[r].y += ev * w.y;
            acc[r].z += ev * w.z; acc[r].w += ev * w.w;
        }
    }
    const float4 bv = ((const float4*)bh)[tid];
#pragma unroll
    for (int r = 0; r < XH_ROWS; ++r) {
        float4 o;
        o.x = acc[r].x + bv.x; o.y = acc[r].y + bv.y;
        o.z = acc[r].z + bv.z; o.w = acc[r].w + bv.w;
        ((float4*)xh)[(size_t)(blk * XH_ROWS + r) * (HIDDEN / 4) + tid] = o;
    }
}

// ---------------- persistent recurrence: u64 token-in-data, 8 chains x 32 members ----------------
// One u64 = token(low16) | bf16 h[2w]<<16 | bf16 h[2w+1]<<32. Producers fire-and-forget
// relaxed agent stores; consumers poll 2 independent u64 per thread in one combined
// retry loop. Double buffer + exact-token match is deadlock-free (induction over steps)
// and replay-safe (stale tokens 255/256 never match expected 0/1).
// RCOLS=32 halves the per-block FMA phase vs RCOLS=64; xh is pre-staged in LDS.
__global__ __launch_bounds__(256, 1) void k_rec(const float* __restrict__ Whh,
                                                const float* __restrict__ xh,
                                                unsigned long long* __restrict__ hx,
                                                __hip_bfloat16* __restrict__ hs) {
    __shared__ unsigned WstU[16 * 1032];   // [part][ii*16+col2], part-padded: 66 KB
    __shared__ float xhS[NT * RCOLS];      // 32 KB, [t][col]
    __shared__ float hS[1024];             // 4 KB
    __shared__ float red[16 * 32];         // 2 KB, [part][2*col2 + parity]
    const int tid = threadIdx.x;
    const int bid = blockIdx.x;
    const int c = bid & (NCH - 1);     // chain (bid%8 ~ XCD round robin)
    const int m = bid >> 3;            // member 0..31
    const int j0 = m * RCOLS;
    unsigned long long* hxc = hx + (size_t)c * 1024;   // [2][512] u64 words

    // h_{-1} = 0 with token 0 lives in buf[1]; this member's 16 words
    if (tid < 16)
        __hip_atomic_store(&hxc[512 + m * 16 + tid], 0ull, __ATOMIC_RELAXED,
                           __HIP_MEMORY_SCOPE_AGENT);

    // pack W_hh slice: row i = part*64+ii, cols j0+2*col2, j0+2*col2+1
    for (int lin = tid; lin < 16 * 64 * 16; lin += 256) {
        const int part = lin >> 10;
        const int rem = lin & 1023;
        const int ii = rem >> 4;
        const int col2 = rem & 15;
        const int i = part * 64 + ii;
        const float2 w = *(const float2*)&Whh[(size_t)i * HIDDEN + j0 + 2 * col2];
        WstU[part * 1032 + ii * 16 + col2] =
            (unsigned)bf16_bits(w.x) | ((unsigned)bf16_bits(w.y) << 16);
    }
    // pre-stage this block's xh slice: [256][32]
    for (int idx = tid; idx < NT * RCOLS; idx += 256) {
        const int t = idx >> 5;
        const int col = idx & 31;
        xhS[idx] = xh[(size_t)(c * NT + t) * HIDDEN + j0 + col];
    }
    __syncthreads();

    const int col2 = tid & 15;
    const int part = tid >> 4;
    const unsigned* Wp = &WstU[part * 1032 + col2];
    const float* hp = &hS[part * 64];
    const int w0 = tid;          // u64 word indices this thread polls
    const int w1 = tid + 256;

    for (int t = 0; t < NT; ++t) {
        unsigned long long* rbuf = hxc + ((t + 1) & 1) * 512;  // h_{t-1}, tokens == t
        unsigned long long* wbuf = hxc + (t & 1) * 512;        // we write h_t, token t+1
        const unsigned long long tok = (unsigned long long)(unsigned)t;
        // combined poll: both loads independent & in flight before the check
        unsigned long long a = __hip_atomic_load(&rbuf[w0], __ATOMIC_RELAXED, __HIP_MEMORY_SCOPE_AGENT);
        unsigned long long b = __hip_atomic_load(&rbuf[w1], __ATOMIC_RELAXED, __HIP_MEMORY_SCOPE_AGENT);
        while (((a & 0xffffull) != tok) | ((b & 0xffffull) != tok)) {
            __builtin_amdgcn_s_sleep(1);
            if ((a & 0xffffull) != tok)
                a = __hip_atomic_load(&rbuf[w0], __ATOMIC_RELAXED, __HIP_MEMORY_SCOPE_AGENT);
            if ((b & 0xffffull) != tok)
                b = __hip_atomic_load(&rbuf[w1], __ATOMIC_RELAXED, __HIP_MEMORY_SCOPE_AGENT);
        }
        hS[2 * w0]     = __uint_as_float(((unsigned)(a >> 16) & 0xffffu) << 16);
        hS[2 * w0 + 1] = __uint_as_float(((unsigned)(a >> 32) & 0xffffu) << 16);
        hS[2 * w1]     = __uint_as_float(((unsigned)(b >> 16) & 0xffffu) << 16);
        hS[2 * w1 + 1] = __uint_as_float(((unsigned)(b >> 32) & 0xffffu) << 16);
        __syncthreads();
        float a0 = 0.f, a1 = 0.f;
#pragma unroll 8
        for (int ii = 0; ii < 64; ++ii) {
            const unsigned u = Wp[ii * 16];
            const float hv = hp[ii];
            a0 = fmaf(__uint_as_float(u << 16), hv, a0);
            a1 = fmaf(__uint_as_float(u & 0xffff0000u), hv, a1);
        }
        red[part * 32 + 2 * col2]     = a0;
        red[part * 32 + 2 * col2 + 1] = a1;
        __syncthreads();
        if (tid < RCOLS) {
            float s = 0.f;
#pragma unroll
            for (int p = 0; p < 16; ++p) s += red[p * 32 + tid];
            const float v = tanhf(xhS[t * RCOLS + tid] + s);
            const unsigned hb = (unsigned)bf16_bits(v);
            ((unsigned short*)hs)[(size_t)(c * NT + t) * HIDDEN + j0 + tid] = (unsigned short)hb;
            const unsigned pb = (unsigned)__shfl_xor((int)hb, 1, 64);
            if ((tid & 1) == 0) {
                const unsigned long long wv = (unsigned long long)(unsigned)(t + 1)
                                            | ((unsigned long long)hb << 16)
                                            | ((unsigned long long)pb << 32);
                __hip_atomic_store(&wbuf[m * 16 + (tid >> 1)], wv, __ATOMIC_RELAXED,
                                   __HIP_MEMORY_SCOPE_AGENT);
            }
        }
        // no block barrier: next step's hS writes are gated by the token poll,
        // which can't pass until this block produced its own words.
    }
}

// ---------------- y = hs @ W_hy + b_y  (bf16 MFMA, fused B transpose+cast) ----------------
#define LDP 40   // padded LDS row: 80 B stride, breaks the 8-way read conflict
__global__ __launch_bounds__(256) void k_proj(const __hip_bfloat16* __restrict__ A,   // [2048][1024]
                                              const float* __restrict__ B,            // [1024][32000]
                                              const float* __restrict__ by,
                                              float* __restrict__ C) {
    __shared__ alignas(16) __hip_bfloat16 At[128][LDP];
    __shared__ alignas(16) __hip_bfloat16 Bts[128][LDP];
    const int tid = threadIdx.x;
    const int m0 = blockIdx.x * 128;   // m fastest: 16 consecutive blocks share a B panel
    const int n0 = blockIdx.y * 128;
    const int lane = tid & 63;
    const int wid = tid >> 6;
    const int wr = wid >> 1, wc = wid & 1;
    const int fr = lane & 15, fq = lane >> 4;
    f32x4 acc[4][4] = {};
    const int sr = tid >> 1;         // A staging row 0..127
    const int sh = (tid & 1) * 16;   // A staging k-offset (16 bf16 per thread)
    const int bkr = tid >> 3;        // B staging k-row 0..31
    const int bc0 = (tid & 7) * 4;   // B staging col base
    for (int k0 = 0; k0 < HIDDEN; k0 += 32) {
        const uint4* As = (const uint4*)(A + (size_t)(m0 + sr) * HIDDEN + k0 + sh);
        uint4 a0v = As[0], a1v = As[1];
        float4 bv[4];
#pragma unroll
        for (int p = 0; p < 4; ++p)
            bv[p] = *(const float4*)(B + (size_t)(k0 + bkr) * VOCAB + n0 + bc0 + p * 32);
        *(uint4*)&At[sr][sh]     = a0v;
        *(uint4*)&At[sr][sh + 8] = a1v;
#pragma unroll
        for (int p = 0; p < 4; ++p) {
            const int cc = bc0 + p * 32;
            Bts[cc + 0][bkr] = __float2bfloat16(bv[p].x);
            Bts[cc + 1][bkr] = __float2bfloat16(bv[p].y);
            Bts[cc + 2][bkr] = __float2bfloat16(bv[p].z);
            Bts[cc + 3][bkr] = __float2bfloat16(bv[p].w);
        }
        __syncthreads();
        bf16x8 af[4], bfr[4];
#pragma unroll
        for (int mm = 0; mm < 4; ++mm) af[mm] = *(const bf16x8*)&At[wr * 64 + mm * 16 + fr][fq * 8];
#pragma unroll
        for (int nn = 0; nn < 4; ++nn) bfr[nn] = *(const bf16x8*)&Bts[wc * 64 + nn * 16 + fr][fq * 8];
#pragma unroll
        for (int mm = 0; mm < 4; ++mm)
#pragma unroll
            for (int nn = 0; nn < 4; ++nn)
                acc[mm][nn] = __builtin_amdgcn_mfma_f32_16x16x32_bf16(af[mm], bfr[nn], acc[mm][nn], 0, 0, 0);
        __syncthreads();
    }
#pragma unroll
    for (int nn = 0; nn < 4; ++nn) {
        const int col = n0 + wc * 64 + nn * 16 + fr;
        const float bias = by[col];
#pragma unroll
        for (int mm = 0; mm < 4; ++mm) {
            const int row = m0 + wr * 64 + mm * 16 + fq * 4;
            float* cp = C + (size_t)row * VOCAB + col;
            cp[0]                 = acc[mm][nn][0] + bias;
            cp[(size_t)VOCAB]     = acc[mm][nn][1] + bias;
            cp[(size_t)2 * VOCAB] = acc[mm][nn][2] + bias;
            cp[(size_t)3 * VOCAB] = acc[mm][nn][3] + bias;
        }
    }
}

extern "C" void kernel_launch(void* const* d_in, const int* in_sizes, int n_in,
                              void* d_out, int out_size, void* d_ws, size_t ws_size,
                              hipStream_t stream) {
    const int*   x   = (const int*)d_in[0];
    const float* emb = (const float*)d_in[1];
    const float* Wxh = (const float*)d_in[2];
    const float* Whh = (const float*)d_in[3];
    const float* bh  = (const float*)d_in[4];
    const float* Why = (const float*)d_in[5];
    const float* by  = (const float*)d_in[6];
    float* y = (float*)d_out;

    char* ws = (char*)d_ws;
    // layout: xh (8 MB) | hx u64[8][2][512] (64 KB) | hs bf16 (4 MB)
    const size_t off_xh = 0;
    const size_t off_hx = off_xh + (size_t)NB * NT * HIDDEN * 4;
    const size_t off_hs = off_hx + (size_t)NCH * 2 * 512 * 8;
    const size_t need   = off_hs + (size_t)NB * NT * HIDDEN * 2;
    if (ws_size < need) return;

    float* xh = (float*)(ws + off_xh);
    unsigned long long* hx = (unsigned long long*)(ws + off_hx);
    __hip_bfloat16* hs = (__hip_bfloat16*)(ws + off_hs);

    k_xh<<<dim3((NB * NT) / XH_ROWS), 256, 0, stream>>>(x, emb, Wxh, bh, xh);
    k_rec<<<dim3(NCH * NMEM), 256, 0, stream>>>(Whh, xh, hx, hs);
    k_proj<<<dim3((NB * NT) / 128, VOCAB / 128), 256, 0, stream>>>(hs, Why, by, y);
}